// Round 7
// baseline (297.467 us; speedup 1.0000x reference)
//
#include <hip/hip_runtime.h>

#define BS 1024
#define D 128
#define NC 100000
#define NCP 100096           /* padded: 1564 * 64 */
#define NT64 1564            /* 64-class tiles */
#define PHASES 256           /* tile phases; grid = 256 x 2 slices = 512 blocks = 2/CU */
#define S_SCALE 30.0f
#define MARGIN 0.35f
#define S2LOG2E 43.2808512f  /* 30 * log2(e): exp(30c-30) == exp2(fma(c,S2,-S2)) */

typedef __attribute__((ext_vector_type(8))) short bf16x8;
typedef __attribute__((ext_vector_type(4))) float f32x4;

#define MFMA(a, b, c) __builtin_amdgcn_mfma_f32_16x16x32_bf16((a), (b), (c), 0, 0, 0)

__device__ __forceinline__ unsigned short f2bf(float f) {
    union { float f; unsigned u; } x; x.f = f;
    unsigned u = x.u;
    u += 0x7FFFu + ((u >> 16) & 1u);   // round-to-nearest-even
    return (unsigned short)(u >> 16);
}

// HW packed f32->bf16 (RNE, same result as f2bf): 1 inst per pair vs ~12.
__device__ __forceinline__ unsigned pkbf(float lo, float hi) {
    unsigned r;
    asm("v_cvt_pk_bf16_f32 %0, %1, %2" : "=v"(r) : "v"(lo), "v"(hi));
    return r;
}

// Fragment-sequential bf16 layout (operand-role-agnostic):
//   u32 index for (row r, k-pair p): (r>>4)*1024 + (p>>2)*64 + (r&15)*4 + (p&3)
// MFMA A-frag read for (rowblock ag, kgroup ks): contiguous 1KB at
//   byte = ag*4096 + ks*1024 + lane*16   (lane = row&15 + 16*kslot)

// 4 rows per block (4 waves): l2-normalize input rows, emit f32 + frag bf16,
// count labels, and pos[row] = S * dot(fn, l2norm(weight[label])) in f32.
__global__ void prep_fn(const float* __restrict__ inp, const int* __restrict__ label,
                        const float* __restrict__ wt,
                        float* __restrict__ fn_f32, unsigned short* __restrict__ fn_fr,
                        float* __restrict__ counts, float* __restrict__ pos) {
    int row = blockIdx.x * 4 + (threadIdx.x >> 6);
    int lane = threadIdx.x & 63;
    float2 v = *(const float2*)(inp + row * D + lane * 2);
    float s = v.x * v.x + v.y * v.y;
    #pragma unroll
    for (int m = 1; m < 64; m <<= 1) s += __shfl_xor(s, m);
    float inv = 1.0f / fmaxf(sqrtf(s), 1e-12f);
    float a = v.x * inv, b = v.y * inv;
    *(float2*)(fn_f32 + row * D + lane * 2) = make_float2(a, b);
    unsigned pack = (unsigned)f2bf(a) | ((unsigned)f2bf(b) << 16);
    ((unsigned*)fn_fr)[(row >> 4) * 1024 + (lane >> 2) * 64 + ((row & 15) << 2) + (lane & 3)] = pack;

    int c = label[row];
    float2 wv = *(const float2*)(wt + c * D + lane * 2);
    float sw_ = wv.x * wv.x + wv.y * wv.y;
    float dt  = wv.x * a + wv.y * b;
    #pragma unroll
    for (int m = 1; m < 64; m <<= 1) { sw_ += __shfl_xor(sw_, m); dt += __shfl_xor(dt, m); }
    if (lane == 0) {
        float invw = 1.0f / fmaxf(sqrtf(sw_), 1e-12f);
        pos[row] = S_SCALE * dt * invw;
        atomicAdd(counts + c, 1.0f);
    }
}

// v9 main: fused normalize+GEMM+exp, restructured vs v7:
//  - 512-thr blocks (8 waves x 64 batch rows): half the waves per barrier,
//    half the chip LDS-read volume (each A-frag feeds 2x the MFMA), 2 blocks/CU.
//  - COMMIT packs via v_cvt_pk_bf16_f32 (1 inst/pair, was ~12) and uses the
//    k-pair-interleaved thread mapping p = g8+8m -> ds_write banks 2-way (free).
//  - class axis in 4 register passes (acc = 16 regs); LOADV (float2 x8,
//    coalesced) issues after pass 0, consumed by COMMIT after pass 3.
// Thread roles: lane/w for MFMA; (rloc = tid>>3, g8 = tid&7) for load/commit:
// thread owns row rloc, k-pairs {g8, g8+8, ..., g8+56} (f32 pairs 8B-coalesced).
#define LOADV() do {                                                          \
    if (rg < NC) {                                                            \
        const float2* p_ = (const float2*)(wt + (size_t)rg * 128) + g8;       \
        v0 = p_[0];  v1 = p_[8];  v2 = p_[16]; v3 = p_[24];                   \
        v4 = p_[32]; v5 = p_[40]; v6 = p_[48]; v7 = p_[56];                   \
    } else {                                                                  \
        v0 = v1 = v2 = v3 = v4 = v5 = v6 = v7 = make_float2(0.f, 0.f);        \
    }                                                                         \
} while (0)

// idx for pair p=g8+8m: b_ + m*128 where b_ = (rloc>>4)*1024 + (g8>>2)*64
//   + (rloc&15)*4 + (g8&3).  Banks: (4*rloc + (g8&3)) % 32 -> 2-way only.
#define COMMIT(buf) do {                                                      \
    float ss = v0.x*v0.x + v0.y*v0.y + v1.x*v1.x + v1.y*v1.y                  \
             + v2.x*v2.x + v2.y*v2.y + v3.x*v3.x + v3.y*v3.y                  \
             + v4.x*v4.x + v4.y*v4.y + v5.x*v5.x + v5.y*v5.y                  \
             + v6.x*v6.x + v6.y*v6.y + v7.x*v7.x + v7.y*v7.y;                 \
    ss += __shfl_xor(ss, 1); ss += __shfl_xor(ss, 2); ss += __shfl_xor(ss, 4);\
    float inv = 1.0f / fmaxf(sqrtf(ss), 1e-12f);                              \
    unsigned* Wu_ = (unsigned*)(buf);                                         \
    int b_ = (rloc >> 4) * 1024 + (g8 >> 2) * 64 + (rloc & 15) * 4 + (g8 & 3);\
    Wu_[b_      ] = pkbf(v0.x * inv, v0.y * inv);                             \
    Wu_[b_ + 128] = pkbf(v1.x * inv, v1.y * inv);                             \
    Wu_[b_ + 256] = pkbf(v2.x * inv, v2.y * inv);                             \
    Wu_[b_ + 384] = pkbf(v3.x * inv, v3.y * inv);                             \
    Wu_[b_ + 512] = pkbf(v4.x * inv, v4.y * inv);                             \
    Wu_[b_ + 640] = pkbf(v5.x * inv, v5.y * inv);                             \
    Wu_[b_ + 768] = pkbf(v6.x * inv, v6.y * inv);                             \
    Wu_[b_ + 896] = pkbf(v7.x * inv, v7.y * inv);                             \
    if (writeout && rg < NC) {                                                \
        float cnt_ = counts[rg];                                              \
        float2* op_ = (float2*)(outw + (size_t)rg * 128) + g8;                \
        float2 z_ = make_float2(0.f, 0.f);                                    \
        op_[0]  = cnt_ > 0.f ? z_ : v0;  op_[8]  = cnt_ > 0.f ? z_ : v1;      \
        op_[16] = cnt_ > 0.f ? z_ : v2;  op_[24] = cnt_ > 0.f ? z_ : v3;      \
        op_[32] = cnt_ > 0.f ? z_ : v4;  op_[40] = cnt_ > 0.f ? z_ : v5;      \
        op_[48] = cnt_ > 0.f ? z_ : v6;  op_[56] = cnt_ > 0.f ? z_ : v7;      \
    }                                                                         \
} while (0)

#define PASS(ag) do {                                                         \
    const char* W_ = (const char*)Ws[cur] + (ag) * 4096 + lane * 16;          \
    f32x4 c0 = (f32x4){0,0,0,0}, c1 = (f32x4){0,0,0,0};                       \
    f32x4 c2 = (f32x4){0,0,0,0}, c3 = (f32x4){0,0,0,0};                       \
    _Pragma("unroll")                                                         \
    for (int ks = 0; ks < 4; ks++) {                                          \
        bf16x8 a_ = *(const bf16x8*)(W_ + ks * 1024);                         \
        c0 = MFMA(a_, bf[0][ks], c0);                                         \
        c1 = MFMA(a_, bf[1][ks], c1);                                         \
        c2 = MFMA(a_, bf[2][ks], c2);                                         \
        c3 = MFMA(a_, bf[3][ks], c3);                                         \
    }                                                                         \
    _Pragma("unroll")                                                         \
    for (int r = 0; r < 4; r++) {                                             \
        sums[0] += __builtin_amdgcn_exp2f(fmaf(c0[r], S2LOG2E, -S2LOG2E));    \
        sums[1] += __builtin_amdgcn_exp2f(fmaf(c1[r], S2LOG2E, -S2LOG2E));    \
        sums[2] += __builtin_amdgcn_exp2f(fmaf(c2[r], S2LOG2E, -S2LOG2E));    \
        sums[3] += __builtin_amdgcn_exp2f(fmaf(c3[r], S2LOG2E, -S2LOG2E));    \
    }                                                                         \
} while (0)

__global__ __launch_bounds__(512, 4) void main_gemm(
    const unsigned short* __restrict__ fnfr, const float* __restrict__ wt,
    const float* __restrict__ counts, float* __restrict__ sumexp,
    float* __restrict__ outw) {
    __shared__ __align__(16) short Ws[2][8192];   // 2 x 16 KB frag tiles
    const int tid = threadIdx.x;
    const int lane = tid & 63, w = tid >> 6;      // 8 waves
    const int g8 = tid & 7;
    const int rloc = tid >> 3;                    // 0..63: tile-local class row
    const int slice = blockIdx.y;                 // batch slice (512 rows)
    const bool writeout = (slice == 0);

    // fn B-fragments in regs (64 VGPRs): wave w owns batch rows slice*512+w*64..+64.
    bf16x8 bf[4][4];  // [cg][ks]
    {
        const char* gB = (const char*)fnfr + (size_t)(slice * 32 + w * 4) * 4096 + lane * 16;
        #pragma unroll
        for (int cg = 0; cg < 4; cg++)
            #pragma unroll
            for (int ks = 0; ks < 4; ks++)
                bf[cg][ks] = *(const bf16x8*)(gB + cg * 4096 + ks * 1024);
    }
    #pragma unroll
    for (int cg = 0; cg < 4; cg++)
        #pragma unroll
        for (int ks = 0; ks < 4; ks++)
            asm volatile("" : "+v"(bf[cg][ks]));

    float sums[4] = {0.0f, 0.0f, 0.0f, 0.0f};
    float2 v0, v1, v2, v3, v4, v5, v6, v7;

    // prologue: tile t0 -> load, normalize, commit to buf 0
    int rg = blockIdx.x * 64 + rloc;
    LOADV();
    COMMIT(Ws[0]);
    __syncthreads();

    int cur = 0;
    for (int t = blockIdx.x; t < NT64; t += PHASES) {
        int nxt = t + PHASES;
        PASS(0);
        if (nxt < NT64) { rg = nxt * 64 + rloc; LOADV(); }   // ~3 passes to land
        PASS(1);
        PASS(2);
        PASS(3);
        if (nxt < NT64) COMMIT(Ws[cur ^ 1]);
        __syncthreads();                       // ds_writes visible for next iter
        cur ^= 1;
    }

    // fold the quad axis (class rows live in quads) and flush once per wave.
    #pragma unroll
    for (int cg = 0; cg < 4; cg++) {
        float s = sums[cg];
        s += __shfl_xor(s, 16);
        s += __shfl_xor(s, 32);
        if (lane < 16)
            atomicAdd(sumexp + slice * 512 + w * 64 + cg * 16 + lane, s);
    }
}

// tail: blocks 0..511 = addmean (2 rows each); block 512 = loss.
__global__ void tail_k(const float* __restrict__ fn_f32, const int* __restrict__ label,
                       const float* __restrict__ counts, float* __restrict__ outw,
                       const float* __restrict__ sumexp, const float* __restrict__ pos,
                       float* __restrict__ out) {
    if (blockIdx.x < 512) {
        int b = blockIdx.x * 2 + (threadIdx.x >> 7);
        int t = threadIdx.x & 127;
        int c = label[b];
        atomicAdd(outw + (size_t)c * D + t, fn_f32[b * D + t] / counts[c]);
        return;
    }
    // loss = mean softplus(M + 30 + log(sum_all - exp(pos-30)) - pos)
    __shared__ float red[256];
    int t = threadIdx.x;
    float acc = 0.0f;
    #pragma unroll
    for (int i = 0; i < 4; i++) {
        int r = t + i * 256;
        float p = pos[r];
        float sneg = fmaxf(sumexp[r] - __expf(p - 30.0f), 1e-38f);
        float lse = 30.0f + logf(sneg);
        float z = MARGIN + lse - p;
        acc += fmaxf(z, 0.0f) + log1pf(__expf(-fabsf(z)));
    }
    red[t] = acc;
    __syncthreads();
    for (int s = 128; s > 0; s >>= 1) {
        if (t < s) red[t] += red[t + s];
        __syncthreads();
    }
    if (t == 0) out[0] = red[0] * (1.0f / 1024.0f);
}

extern "C" void kernel_launch(void* const* d_in, const int* in_sizes, int n_in,
                              void* d_out, int out_size, void* d_ws, size_t ws_size,
                              hipStream_t stream) {
    (void)in_sizes; (void)n_in; (void)out_size; (void)ws_size;
    const float* inp   = (const float*)d_in[0];
    const int*   label = (const int*)d_in[1];
    const float* wt    = (const float*)d_in[2];
    float* out = (float*)d_out;

    char* w = (char*)d_ws;
    float*          fn_f32 = (float*)(w);                     // 524288 B
    unsigned short* fn_fr  = (unsigned short*)(w + 524288);   // 262144 B
    float*          sumexp = (float*)(w + 26411008);          // 4096 B
    float*          counts = (float*)(w + 26415104);          // 400000 B
    float*          pos    = (float*)(w + 26815104);          // 4096 B

    // zero sumexp + counts (contiguous)
    hipMemsetAsync(w + 26411008, 0, 404096, stream);

    prep_fn<<<BS / 4, 256, 0, stream>>>(inp, label, wt, fn_f32, fn_fr, counts, pos);
    main_gemm<<<dim3(PHASES, 2), 512, 0, stream>>>(fn_fr, wt, counts, sumexp, out + 1);
    tail_k<<<513, 256, 0, stream>>>(fn_f32, label, counts, out + 1, sumexp, pos, out);
}

// Round 8
// 141.484 us; speedup vs baseline: 2.1025x; 2.1025x over previous
//
#include <hip/hip_runtime.h>

#define BS 1024
#define D 128
#define NC 100000
#define NCP 100096           /* padded: 1564 * 64 */
#define NT64 1564            /* 64-class tiles */
#define PHASES 256           /* tile phases; grid = 256 x 4 slices = 1024 blocks */
#define S_SCALE 30.0f
#define MARGIN 0.35f
#define S2LOG2E 43.2808512f  /* 30 * log2(e): exp(30c-30) == exp2(fma(c,S2,-S2)) */

typedef __attribute__((ext_vector_type(8))) short bf16x8;
typedef __attribute__((ext_vector_type(4))) float f32x4;

#define MFMA(a, b, c) __builtin_amdgcn_mfma_f32_16x16x32_bf16((a), (b), (c), 0, 0, 0)

__device__ __forceinline__ unsigned short f2bf(float f) {
    union { float f; unsigned u; } x; x.f = f;
    unsigned u = x.u;
    u += 0x7FFFu + ((u >> 16) & 1u);   // round-to-nearest-even
    return (unsigned short)(u >> 16);
}

// HW packed f32->bf16 (RNE, bit-identical to f2bf): 1 inst per pair vs ~12.
__device__ __forceinline__ unsigned pkbf(float lo, float hi) {
    unsigned r;
    asm("v_cvt_pk_bf16_f32 %0, %1, %2" : "=v"(r) : "v"(lo), "v"(hi));
    return r;
}

// Fragment-sequential bf16 layout (operand-role-agnostic):
//   u32 index for (row r, k-pair p): (r>>4)*1024 + (p>>2)*64 + (r&15)*4 + (p&3)
// MFMA A-frag read for (rowblock ag, kgroup ks): contiguous 1KB at
//   byte = ag*4096 + ks*1024 + lane*16   (lane = row&15 + 16*kslot)

// 4 rows per block (4 waves): l2-normalize input rows, emit f32 + frag bf16,
// count labels, and pos[row] = S * dot(fn, l2norm(weight[label])) in f32.
__global__ void prep_fn(const float* __restrict__ inp, const int* __restrict__ label,
                        const float* __restrict__ wt,
                        float* __restrict__ fn_f32, unsigned short* __restrict__ fn_fr,
                        float* __restrict__ counts, float* __restrict__ pos) {
    int row = blockIdx.x * 4 + (threadIdx.x >> 6);
    int lane = threadIdx.x & 63;
    float2 v = *(const float2*)(inp + row * D + lane * 2);
    float s = v.x * v.x + v.y * v.y;
    #pragma unroll
    for (int m = 1; m < 64; m <<= 1) s += __shfl_xor(s, m);
    float inv = 1.0f / fmaxf(sqrtf(s), 1e-12f);
    float a = v.x * inv, b = v.y * inv;
    *(float2*)(fn_f32 + row * D + lane * 2) = make_float2(a, b);
    unsigned pack = (unsigned)f2bf(a) | ((unsigned)f2bf(b) << 16);
    ((unsigned*)fn_fr)[(row >> 4) * 1024 + (lane >> 2) * 64 + ((row & 15) << 2) + (lane & 3)] = pack;

    int c = label[row];
    float2 wv = *(const float2*)(wt + c * D + lane * 2);
    float sw_ = wv.x * wv.x + wv.y * wv.y;
    float dt  = wv.x * a + wv.y * b;
    #pragma unroll
    for (int m = 1; m < 64; m <<= 1) { sw_ += __shfl_xor(sw_, m); dt += __shfl_xor(dt, m); }
    if (lane == 0) {
        float invw = 1.0f / fmaxf(sqrtf(sw_), 1e-12f);
        pos[row] = S_SCALE * dt * invw;
        atomicAdd(counts + c, 1.0f);
    }
}

// v10 main: fused normalize+GEMM+exp. Changes vs v7 (R6, 53us):
//  - 512-thr / 8-wave blocks, 4 batch slices: per-wave shape identical to v7
//    (bf[2][4] 32-reg pin, 2 cg) but total regfile ~96/wave -> TWO blocks
//    resident per CU (16 waves x 96 <= 2048), giving cross-block MFMA/VALU
//    overlap during barrier+commit phases. v9's spill (VGPR capped at 64,
//    640 MB scratch) came from a 130-reg design; this one fits ~64+AGPR.
//  - per-pass exp (c0,c1 = 8 live accs, was acc[4][2]=32) + wave rotation
//    rot=(w>>2)&3 so SIMD-mates sit in different MFMA/exp phases.
//  - COMMIT packs via v_cvt_pk_bf16_f32 (1 inst/pair, was ~12).
// Thread roles: lane/w for MFMA; (rloc = tid>>3, g8 = tid&7): thread owns
// class row rloc, k-pairs {g8, g8+8, ..., g8+56} (8B-coalesced f32 pairs).
#define LOADV() do {                                                          \
    if (rg < NC) {                                                            \
        const float2* p_ = (const float2*)(wt + (size_t)rg * 128) + g8;       \
        v0 = p_[0];  v1 = p_[8];  v2 = p_[16]; v3 = p_[24];                   \
        v4 = p_[32]; v5 = p_[40]; v6 = p_[48]; v7 = p_[56];                   \
    } else {                                                                  \
        v0 = v1 = v2 = v3 = v4 = v5 = v6 = v7 = make_float2(0.f, 0.f);        \
    }                                                                         \
} while (0)

// idx for pair p=g8+8m: b_ + m*128, b_ = (rloc>>4)*1024 + (g8>>2)*64
//   + (rloc&15)*4 + (g8&3).
#define COMMIT(buf) do {                                                      \
    float ss = v0.x*v0.x + v0.y*v0.y + v1.x*v1.x + v1.y*v1.y                  \
             + v2.x*v2.x + v2.y*v2.y + v3.x*v3.x + v3.y*v3.y                  \
             + v4.x*v4.x + v4.y*v4.y + v5.x*v5.x + v5.y*v5.y                  \
             + v6.x*v6.x + v6.y*v6.y + v7.x*v7.x + v7.y*v7.y;                 \
    ss += __shfl_xor(ss, 1); ss += __shfl_xor(ss, 2); ss += __shfl_xor(ss, 4);\
    float inv = 1.0f / fmaxf(sqrtf(ss), 1e-12f);                              \
    unsigned* Wu_ = (unsigned*)(buf);                                         \
    int b_ = (rloc >> 4) * 1024 + (g8 >> 2) * 64 + (rloc & 15) * 4 + (g8 & 3);\
    Wu_[b_      ] = pkbf(v0.x * inv, v0.y * inv);                             \
    Wu_[b_ + 128] = pkbf(v1.x * inv, v1.y * inv);                             \
    Wu_[b_ + 256] = pkbf(v2.x * inv, v2.y * inv);                             \
    Wu_[b_ + 384] = pkbf(v3.x * inv, v3.y * inv);                             \
    Wu_[b_ + 512] = pkbf(v4.x * inv, v4.y * inv);                             \
    Wu_[b_ + 640] = pkbf(v5.x * inv, v5.y * inv);                             \
    Wu_[b_ + 768] = pkbf(v6.x * inv, v6.y * inv);                             \
    Wu_[b_ + 896] = pkbf(v7.x * inv, v7.y * inv);                             \
    if (writeout && rg < NC) {                                                \
        float cnt_ = counts[rg];                                              \
        float2* op_ = (float2*)(outw + (size_t)rg * 128) + g8;                \
        float2 z_ = make_float2(0.f, 0.f);                                    \
        op_[0]  = cnt_ > 0.f ? z_ : v0;  op_[8]  = cnt_ > 0.f ? z_ : v1;      \
        op_[16] = cnt_ > 0.f ? z_ : v2;  op_[24] = cnt_ > 0.f ? z_ : v3;      \
        op_[32] = cnt_ > 0.f ? z_ : v4;  op_[40] = cnt_ > 0.f ? z_ : v5;      \
        op_[48] = cnt_ > 0.f ? z_ : v6;  op_[56] = cnt_ > 0.f ? z_ : v7;      \
    }                                                                         \
} while (0)

__global__ __launch_bounds__(512, 4) void main_gemm(
    const unsigned short* __restrict__ fnfr, const float* __restrict__ wt,
    const float* __restrict__ counts, float* __restrict__ sumexp,
    float* __restrict__ outw) {
    __shared__ __align__(16) short Ws[2][8192];   // 2 x 16 KB frag tiles
    const int tid = threadIdx.x;
    const int lane = tid & 63, w = tid >> 6;      // 8 waves
    const int g8 = tid & 7;
    const int rloc = tid >> 3;                    // 0..63: tile-local class row
    const int slice = blockIdx.y;                 // batch slice (256 rows)
    const bool writeout = (slice == 0);
    const int rot = (w >> 2) & 3;                 // SIMD-mates (w, w+4) differ

    // fn B-fragments in regs (32 VGPRs): wave w owns batch rows slice*256+w*32..+32.
    bf16x8 bf[2][4];  // [cg][ks]
    {
        const char* gB = (const char*)fnfr + (size_t)(slice * 16 + w * 2) * 4096 + lane * 16;
        #pragma unroll
        for (int cg = 0; cg < 2; cg++)
            #pragma unroll
            for (int ks = 0; ks < 4; ks++)
                bf[cg][ks] = *(const bf16x8*)(gB + cg * 4096 + ks * 1024);
    }
    #pragma unroll
    for (int cg = 0; cg < 2; cg++)
        #pragma unroll
        for (int ks = 0; ks < 4; ks++)
            asm volatile("" : "+v"(bf[cg][ks]));

    float sums[2] = {0.0f, 0.0f};
    float2 v0, v1, v2, v3, v4, v5, v6, v7;

    // prologue: tile t0 -> load, normalize, commit to buf 0
    int rg = blockIdx.x * 64 + rloc;
    LOADV();
    COMMIT(Ws[0]);
    __syncthreads();

    int cur = 0;
    for (int t = blockIdx.x; t < NT64; t += PHASES) {
        int nxt = t + PHASES;
        if (nxt < NT64) { rg = nxt * 64 + rloc; LOADV(); }   // full tile to land

        #pragma unroll
        for (int pp = 0; pp < 4; pp++) {
            int ag = (pp + rot) & 3;
            const char* W_ = (const char*)Ws[cur] + ag * 4096 + lane * 16;
            f32x4 c0 = (f32x4){0.f, 0.f, 0.f, 0.f};
            f32x4 c1 = (f32x4){0.f, 0.f, 0.f, 0.f};
            #pragma unroll
            for (int ks = 0; ks < 4; ks++) {
                bf16x8 a_ = *(const bf16x8*)(W_ + ks * 1024);
                c0 = MFMA(a_, bf[0][ks], c0);
                c1 = MFMA(a_, bf[1][ks], c1);
            }
            #pragma unroll
            for (int r = 0; r < 4; r++) {
                sums[0] += __builtin_amdgcn_exp2f(fmaf(c0[r], S2LOG2E, -S2LOG2E));
                sums[1] += __builtin_amdgcn_exp2f(fmaf(c1[r], S2LOG2E, -S2LOG2E));
            }
        }

        if (nxt < NT64) COMMIT(Ws[cur ^ 1]);   // loads had 4 MFMA+exp passes to land
        __syncthreads();                       // ds_writes visible for next iter
        cur ^= 1;
    }

    // fold the quad axis (class rows live in quads) and flush once per wave.
    #pragma unroll
    for (int cg = 0; cg < 2; cg++) {
        float s = sums[cg];
        s += __shfl_xor(s, 16);
        s += __shfl_xor(s, 32);
        if (lane < 16)
            atomicAdd(sumexp + slice * 256 + w * 32 + cg * 16 + lane, s);
    }
}

// tail: blocks 0..511 = addmean (2 rows each); block 512 = loss.
__global__ void tail_k(const float* __restrict__ fn_f32, const int* __restrict__ label,
                       const float* __restrict__ counts, float* __restrict__ outw,
                       const float* __restrict__ sumexp, const float* __restrict__ pos,
                       float* __restrict__ out) {
    if (blockIdx.x < 512) {
        int b = blockIdx.x * 2 + (threadIdx.x >> 7);
        int t = threadIdx.x & 127;
        int c = label[b];
        atomicAdd(outw + (size_t)c * D + t, fn_f32[b * D + t] / counts[c]);
        return;
    }
    // loss = mean softplus(M + 30 + log(sum_all - exp(pos-30)) - pos)
    __shared__ float red[256];
    int t = threadIdx.x;
    float acc = 0.0f;
    #pragma unroll
    for (int i = 0; i < 4; i++) {
        int r = t + i * 256;
        float p = pos[r];
        float sneg = fmaxf(sumexp[r] - __expf(p - 30.0f), 1e-38f);
        float lse = 30.0f + logf(sneg);
        float z = MARGIN + lse - p;
        acc += fmaxf(z, 0.0f) + log1pf(__expf(-fabsf(z)));
    }
    red[t] = acc;
    __syncthreads();
    for (int s = 128; s > 0; s >>= 1) {
        if (t < s) red[t] += red[t + s];
        __syncthreads();
    }
    if (t == 0) out[0] = red[0] * (1.0f / 1024.0f);
}

extern "C" void kernel_launch(void* const* d_in, const int* in_sizes, int n_in,
                              void* d_out, int out_size, void* d_ws, size_t ws_size,
                              hipStream_t stream) {
    (void)in_sizes; (void)n_in; (void)out_size; (void)ws_size;
    const float* inp   = (const float*)d_in[0];
    const int*   label = (const int*)d_in[1];
    const float* wt    = (const float*)d_in[2];
    float* out = (float*)d_out;

    char* w = (char*)d_ws;
    float*          fn_f32 = (float*)(w);                     // 524288 B
    unsigned short* fn_fr  = (unsigned short*)(w + 524288);   // 262144 B
    float*          sumexp = (float*)(w + 26411008);          // 4096 B
    float*          counts = (float*)(w + 26415104);          // 400000 B
    float*          pos    = (float*)(w + 26815104);          // 4096 B

    // zero sumexp + counts (contiguous)
    hipMemsetAsync(w + 26411008, 0, 404096, stream);

    prep_fn<<<BS / 4, 256, 0, stream>>>(inp, label, wt, fn_f32, fn_fr, counts, pos);
    main_gemm<<<dim3(PHASES, 4), 512, 0, stream>>>(fn_fr, wt, counts, sumexp, out + 1);
    tail_k<<<513, 256, 0, stream>>>(fn_f32, label, counts, out + 1, sumexp, pos, out);
}